// Round 1
// baseline (1709.220 us; speedup 1.0000x reference)
//
#include <hip/hip_runtime.h>
#include <hip/hip_bf16.h>

#define DMODEL 1024
#define NHEAD 16
#define HDIM 64          // DMODEL / NHEAD
#define CTXLEN 2048
#define BATCH 2
#define M_TOTAL (BATCH * CTXLEN)   // 4096

// ---------------------------------------------------------------------------
// GEMM (NT): C[M,N] = A[M,K] * B[N,K]^T  (+ optional bias[N])
// BM=BN=64, BK=16, 256 threads, 4x4 accumulators per thread. fp32 vector ALU.
// ---------------------------------------------------------------------------
__global__ __launch_bounds__(256)
void gemm_nt_f32(const float* __restrict__ A, const float* __restrict__ B,
                 const float* __restrict__ bias, float* __restrict__ C,
                 int M, int N, int K) {
    constexpr int BM = 64, BN = 64, BK = 16;
    __shared__ float As[BK][BM + 4];   // +4 pad keeps 16B alignment & breaks bank stride
    __shared__ float Bs[BK][BN + 4];

    const int tid = threadIdx.x;
    const int tx = tid & 15;    // col group 0..15
    const int ty = tid >> 4;    // row group 0..15
    const int row0 = blockIdx.y * BM;
    const int col0 = blockIdx.x * BN;

    // staging indices: 1024 floats per tile = 256 float4, one per thread
    const int lr = tid >> 2;          // tile row 0..63
    const int lk = (tid & 3) * 4;     // k offset 0,4,8,12

    float acc[4][4] = {};

    for (int k0 = 0; k0 < K; k0 += BK) {
        const float4 av = *reinterpret_cast<const float4*>(&A[(size_t)(row0 + lr) * K + k0 + lk]);
        const float4 bv = *reinterpret_cast<const float4*>(&B[(size_t)(col0 + lr) * K + k0 + lk]);
        __syncthreads();   // previous-iter readers done before overwrite
        As[lk + 0][lr] = av.x; As[lk + 1][lr] = av.y; As[lk + 2][lr] = av.z; As[lk + 3][lr] = av.w;
        Bs[lk + 0][lr] = bv.x; Bs[lk + 1][lr] = bv.y; Bs[lk + 2][lr] = bv.z; Bs[lk + 3][lr] = bv.w;
        __syncthreads();

        #pragma unroll
        for (int kk = 0; kk < BK; ++kk) {
            const float4 a4 = *reinterpret_cast<const float4*>(&As[kk][ty * 4]);
            const float4 b4 = *reinterpret_cast<const float4*>(&Bs[kk][tx * 4]);
            const float a[4] = {a4.x, a4.y, a4.z, a4.w};
            const float b[4] = {b4.x, b4.y, b4.z, b4.w};
            #pragma unroll
            for (int i = 0; i < 4; ++i)
                #pragma unroll
                for (int j = 0; j < 4; ++j)
                    acc[i][j] = fmaf(a[i], b[j], acc[i][j]);
        }
    }

    #pragma unroll
    for (int i = 0; i < 4; ++i) {
        const int r = row0 + ty * 4 + i;
        #pragma unroll
        for (int j = 0; j < 4; ++j) {
            const int c = col0 + tx * 4 + j;
            float v = acc[i][j];
            if (bias) v += bias[c];
            C[(size_t)r * N + c] = v;
        }
    }
}

// ---------------------------------------------------------------------------
// Flash-style causal attention, fp32.
// Grid: (T/QBLK, BATCH*NHEAD). Block: 256 threads = 64 rows x 4 lanes.
// qkv layout: [B, T, 3*DMODEL] with q at +0, k at +DMODEL, v at +2*DMODEL.
// Logits = (q . k) * 8.0  (reference multiplies by sqrt(HDIM)).
// Output y: [B, T, DMODEL] with head h at channels h*HDIM..h*HDIM+63.
// ---------------------------------------------------------------------------
#define QBLK 64
#define KBLK 64

__global__ __launch_bounds__(256)
void attn_fwd_f32(const float* __restrict__ qkv, float* __restrict__ y) {
    const int qb = blockIdx.x;                 // q block
    const int bh = blockIdx.y;                 // b*NHEAD + h
    const int b = bh / NHEAD;
    const int h = bh % NHEAD;

    __shared__ float Qs[QBLK][HDIM + 4];
    __shared__ float Ks[KBLK][HDIM + 4];
    __shared__ float Vs[KBLK][HDIM + 4];
    __shared__ float Ps[QBLK][KBLK + 4];

    const int tid = threadIdx.x;
    const int r   = tid >> 2;   // row 0..63
    const int sub = tid & 3;    // lane-within-row 0..3

    const size_t rs = 3 * DMODEL;   // qkv row stride
    const float* qbase = qkv + (size_t)b * CTXLEN * rs + h * HDIM;
    const float* kbase = qbase + DMODEL;
    const float* vbase = qbase + 2 * DMODEL;

    // load Q tile: 64x64 floats = 1024 float4, 4 per thread (coalesced)
    #pragma unroll
    for (int i = 0; i < 4; ++i) {
        const int idx = i * 256 + tid;
        const int rr = idx >> 4;
        const int c4 = (idx & 15) * 4;
        const float4 v4 = *reinterpret_cast<const float4*>(
            &qbase[(size_t)(qb * QBLK + rr) * rs + c4]);
        Qs[rr][c4 + 0] = v4.x; Qs[rr][c4 + 1] = v4.y;
        Qs[rr][c4 + 2] = v4.z; Qs[rr][c4 + 3] = v4.w;
    }

    float m = -INFINITY, l = 0.0f;
    float yacc[16];
    #pragma unroll
    for (int j = 0; j < 16; ++j) yacc[j] = 0.0f;

    const int qidx = qb * QBLK + r;
    const int nkb = qb + 1;   // causal: only k-blocks <= q-block

    for (int kb = 0; kb < nkb; ++kb) {
        __syncthreads();   // previous-iter Ps/Vs readers done
        #pragma unroll
        for (int i = 0; i < 4; ++i) {
            const int idx = i * 256 + tid;
            const int rr = idx >> 4;
            const int c4 = (idx & 15) * 4;
            const size_t off = (size_t)(kb * KBLK + rr) * rs + c4;
            const float4 kv = *reinterpret_cast<const float4*>(&kbase[off]);
            Ks[rr][c4 + 0] = kv.x; Ks[rr][c4 + 1] = kv.y;
            Ks[rr][c4 + 2] = kv.z; Ks[rr][c4 + 3] = kv.w;
            const float4 vv = *reinterpret_cast<const float4*>(&vbase[off]);
            Vs[rr][c4 + 0] = vv.x; Vs[rr][c4 + 1] = vv.y;
            Vs[rr][c4 + 2] = vv.z; Vs[rr][c4 + 3] = vv.w;
        }
        __syncthreads();

        // S[r][c] for this thread's 16 columns c = sub*16 + j
        float s[16];
        #pragma unroll
        for (int j = 0; j < 16; ++j) s[j] = 0.0f;
        #pragma unroll 4
        for (int d4 = 0; d4 < HDIM; d4 += 4) {
            const float4 q4 = *reinterpret_cast<const float4*>(&Qs[r][d4]);
            #pragma unroll
            for (int j = 0; j < 16; ++j) {
                const float4 k4 = *reinterpret_cast<const float4*>(&Ks[sub * 16 + j][d4]);
                s[j] = fmaf(q4.x, k4.x, s[j]);
                s[j] = fmaf(q4.y, k4.y, s[j]);
                s[j] = fmaf(q4.z, k4.z, s[j]);
                s[j] = fmaf(q4.w, k4.w, s[j]);
            }
        }
        const int kbase_idx = kb * KBLK;
        #pragma unroll
        for (int j = 0; j < 16; ++j) {
            const int kidx = kbase_idx + sub * 16 + j;
            s[j] = (kidx <= qidx) ? s[j] * 8.0f : -INFINITY;
        }

        // row max across 16 local + 4 lanes
        float mx = s[0];
        #pragma unroll
        for (int j = 1; j < 16; ++j) mx = fmaxf(mx, s[j]);
        mx = fmaxf(mx, __shfl_xor(mx, 1));
        mx = fmaxf(mx, __shfl_xor(mx, 2));
        const float mnew = fmaxf(m, mx);          // finite after kb=0 (col 0 unmasked)
        const float corr = __expf(m - mnew);      // first iter: exp(-inf)=0

        float p[16];
        float psum = 0.0f;
        #pragma unroll
        for (int j = 0; j < 16; ++j) { p[j] = __expf(s[j] - mnew); psum += p[j]; }
        psum += __shfl_xor(psum, 1);
        psum += __shfl_xor(psum, 2);
        l = l * corr + psum;
        m = mnew;
        #pragma unroll
        for (int j = 0; j < 16; ++j) yacc[j] *= corr;

        #pragma unroll
        for (int j = 0; j < 16; ++j) Ps[r][sub * 16 + j] = p[j];
        __syncthreads();

        // yacc[d] for d = sub*16 + j, accumulate over all 64 columns
        #pragma unroll 8
        for (int c = 0; c < KBLK; ++c) {
            const float pv = Ps[r][c];
            const float4 v0 = *reinterpret_cast<const float4*>(&Vs[c][sub * 16 + 0]);
            const float4 v1 = *reinterpret_cast<const float4*>(&Vs[c][sub * 16 + 4]);
            const float4 v2 = *reinterpret_cast<const float4*>(&Vs[c][sub * 16 + 8]);
            const float4 v3 = *reinterpret_cast<const float4*>(&Vs[c][sub * 16 + 12]);
            yacc[0]  = fmaf(pv, v0.x, yacc[0]);  yacc[1]  = fmaf(pv, v0.y, yacc[1]);
            yacc[2]  = fmaf(pv, v0.z, yacc[2]);  yacc[3]  = fmaf(pv, v0.w, yacc[3]);
            yacc[4]  = fmaf(pv, v1.x, yacc[4]);  yacc[5]  = fmaf(pv, v1.y, yacc[5]);
            yacc[6]  = fmaf(pv, v1.z, yacc[6]);  yacc[7]  = fmaf(pv, v1.w, yacc[7]);
            yacc[8]  = fmaf(pv, v2.x, yacc[8]);  yacc[9]  = fmaf(pv, v2.y, yacc[9]);
            yacc[10] = fmaf(pv, v2.z, yacc[10]); yacc[11] = fmaf(pv, v2.w, yacc[11]);
            yacc[12] = fmaf(pv, v3.x, yacc[12]); yacc[13] = fmaf(pv, v3.y, yacc[13]);
            yacc[14] = fmaf(pv, v3.z, yacc[14]); yacc[15] = fmaf(pv, v3.w, yacc[15]);
        }
    }

    const float inv = 1.0f / l;
    float* yrow = y + (size_t)(b * CTXLEN + qidx) * DMODEL + h * HDIM + sub * 16;
    #pragma unroll
    for (int j = 0; j < 16; ++j) yrow[j] = yacc[j] * inv;
}

// ---------------------------------------------------------------------------
extern "C" void kernel_launch(void* const* d_in, const int* in_sizes, int n_in,
                              void* d_out, int out_size, void* d_ws, size_t ws_size,
                              hipStream_t stream) {
    const float* x      = (const float*)d_in[0];   // [B, T, C]
    const float* w_qkv  = (const float*)d_in[1];   // [3C, C]
    const float* w_proj = (const float*)d_in[2];   // [C, C]
    const float* b_proj = (const float*)d_in[3];   // [C]
    float* out = (float*)d_out;                    // [B, T, C]

    // workspace: qkv [4096, 3072] fp32 (50.3 MB), y [4096, 1024] fp32 (16.8 MB)
    float* qkv = (float*)d_ws;
    float* y   = qkv + (size_t)M_TOTAL * 3 * DMODEL;

    const dim3 blk(256);

    // 1) qkv = x @ w_qkv^T       M=4096, N=3072, K=1024
    gemm_nt_f32<<<dim3(3 * DMODEL / 64, M_TOTAL / 64), blk, 0, stream>>>(
        x, w_qkv, nullptr, qkv, M_TOTAL, 3 * DMODEL, DMODEL);

    // 2) causal flash attention per (b, h)
    attn_fwd_f32<<<dim3(CTXLEN / QBLK, BATCH * NHEAD), blk, 0, stream>>>(qkv, y);

    // 3) out = y @ w_proj^T + b_proj    M=4096, N=1024, K=1024
    gemm_nt_f32<<<dim3(DMODEL / 64, M_TOTAL / 64), blk, 0, stream>>>(
        y, w_proj, b_proj, out, M_TOTAL, DMODEL, DMODEL);
}

// Round 2
// 677.069 us; speedup vs baseline: 2.5244x; 2.5244x over previous
//
#include <hip/hip_runtime.h>
#include <hip/hip_bf16.h>

#define DMODEL 1024
#define NHEAD 16
#define HDIM 64          // DMODEL / NHEAD
#define CTXLEN 2048
#define BATCH 2
#define M_TOTAL (BATCH * CTXLEN)   // 4096

typedef __attribute__((ext_vector_type(8))) short bf16x8;
typedef __attribute__((ext_vector_type(4))) float f32x4;
typedef __attribute__((ext_vector_type(4))) unsigned short u16x4;

__device__ inline unsigned short f32_bf16(float f) {
    unsigned u = __builtin_bit_cast(unsigned, f);
    u += 0x7FFFu + ((u >> 16) & 1u);
    return (unsigned short)(u >> 16);
}
__device__ inline float bf16_f32(unsigned short h) {
    unsigned u = ((unsigned)h) << 16;
    return __builtin_bit_cast(float, u);
}
__device__ inline f32x4 mfma16(bf16x8 a, bf16x8 b, f32x4 c) {
    return __builtin_amdgcn_mfma_f32_16x16x32_bf16(a, b, c, 0, 0, 0);
}

// ---------------------------------------------------------------------------
// GEMM (NT): C[M,N] = A[M,K] * B[N,K]^T  (+ optional bias[N]) — fp32 VALU
// ---------------------------------------------------------------------------
__global__ __launch_bounds__(256)
void gemm_nt_f32(const float* __restrict__ A, const float* __restrict__ B,
                 const float* __restrict__ bias, float* __restrict__ C,
                 int M, int N, int K) {
    constexpr int BM = 64, BN = 64, BK = 16;
    __shared__ float As[BK][BM + 4];
    __shared__ float Bs[BK][BN + 4];

    const int tid = threadIdx.x;
    const int tx = tid & 15;
    const int ty = tid >> 4;
    const int row0 = blockIdx.y * BM;
    const int col0 = blockIdx.x * BN;
    const int lr = tid >> 2;
    const int lk = (tid & 3) * 4;

    float acc[4][4] = {};

    for (int k0 = 0; k0 < K; k0 += BK) {
        const float4 av = *reinterpret_cast<const float4*>(&A[(size_t)(row0 + lr) * K + k0 + lk]);
        const float4 bv = *reinterpret_cast<const float4*>(&B[(size_t)(col0 + lr) * K + k0 + lk]);
        __syncthreads();
        As[lk + 0][lr] = av.x; As[lk + 1][lr] = av.y; As[lk + 2][lr] = av.z; As[lk + 3][lr] = av.w;
        Bs[lk + 0][lr] = bv.x; Bs[lk + 1][lr] = bv.y; Bs[lk + 2][lr] = bv.z; Bs[lk + 3][lr] = bv.w;
        __syncthreads();

        #pragma unroll
        for (int kk = 0; kk < BK; ++kk) {
            const float4 a4 = *reinterpret_cast<const float4*>(&As[kk][ty * 4]);
            const float4 b4 = *reinterpret_cast<const float4*>(&Bs[kk][tx * 4]);
            const float a[4] = {a4.x, a4.y, a4.z, a4.w};
            const float b[4] = {b4.x, b4.y, b4.z, b4.w};
            #pragma unroll
            for (int i = 0; i < 4; ++i)
                #pragma unroll
                for (int j = 0; j < 4; ++j)
                    acc[i][j] = fmaf(a[i], b[j], acc[i][j]);
        }
    }

    #pragma unroll
    for (int i = 0; i < 4; ++i) {
        const int r = row0 + ty * 4 + i;
        #pragma unroll
        for (int j = 0; j < 4; ++j) {
            const int c = col0 + tx * 4 + j;
            float v = acc[i][j];
            if (bias) v += bias[c];
            C[(size_t)r * N + c] = v;
        }
    }
}

// ---------------------------------------------------------------------------
// Flash causal attention, bf16 MFMA (hi/lo split QK^T for precision).
// Grid: (T/64, B*NHEAD). Block: 256 = 4 waves; wave w owns q-rows 16w..16w+15.
// 16x16x32 MFMA. A-frag: row=lane&15, k=(lane>>4)*8+j. B-frag: col=lane&15.
// D: col=lane&15, row=(lane>>4)*4+reg.
// LDS rows stride 72 ushorts (144 B): rows alias only 8-apart -> <=2-way.
// ---------------------------------------------------------------------------
#define LDSS 72

__global__ __launch_bounds__(256)
void attn_fwd_mfma(const float* __restrict__ qkv, float* __restrict__ y) {
    __shared__ __align__(16) unsigned short Ksh[64][LDSS];   // K hi (also Q hi stage)
    __shared__ __align__(16) unsigned short Ksl[64][LDSS];   // K lo (also Q lo stage)
    __shared__ __align__(16) unsigned short Vt [64][LDSS];   // V transposed [d][kpos]
    __shared__ __align__(16) unsigned short Ps [4][16][LDSS];// per-wave P tile

    const int qb = (int)gridDim.x - 1 - (int)blockIdx.x;  // long blocks first
    const int bh = blockIdx.y;
    const int b  = bh >> 4;
    const int h  = bh & 15;

    const int tid  = threadIdx.x;
    const int wave = tid >> 6;
    const int lane = tid & 63;
    const int lc   = lane & 15;   // col within 16-tile
    const int lg   = lane >> 4;   // 4-lane-group id 0..3

    const size_t rs = 3 * DMODEL;
    const float* qbase = qkv + (size_t)b * CTXLEN * rs + h * HDIM;
    const float* kbase = qbase + DMODEL;
    const float* vbase = qbase + 2 * DMODEL;

    // ---- stage Q (hi/lo) through Ksh/Ksl once; keep frags in registers ----
    #pragma unroll
    for (int i = 0; i < 4; ++i) {
        const int idx = i * 256 + tid;
        const int rr  = idx >> 4;
        const int c4  = (idx & 15) * 4;
        const float4 v = *reinterpret_cast<const float4*>(
            &qbase[(size_t)(qb * 64 + rr) * rs + c4]);
        const float f[4] = {v.x, v.y, v.z, v.w};
        u16x4 hi, lo;
        #pragma unroll
        for (int j = 0; j < 4; ++j) {
            const unsigned short hu = f32_bf16(f[j]);
            hi[j] = hu;
            lo[j] = f32_bf16(f[j] - bf16_f32(hu));
        }
        *reinterpret_cast<u16x4*>(&Ksh[rr][c4]) = hi;
        *reinterpret_cast<u16x4*>(&Ksl[rr][c4]) = lo;
    }
    __syncthreads();
    bf16x8 qh[2], ql[2];
    #pragma unroll
    for (int d = 0; d < 2; ++d) {
        qh[d] = *reinterpret_cast<const bf16x8*>(&Ksh[wave * 16 + lc][d * 32 + lg * 8]);
        ql[d] = *reinterpret_cast<const bf16x8*>(&Ksl[wave * 16 + lc][d * 32 + lg * 8]);
    }

    const f32x4 zero4 = {0.f, 0.f, 0.f, 0.f};
    f32x4 yacc[4];
    #pragma unroll
    for (int t = 0; t < 4; ++t) yacc[t] = zero4;
    float m_i[4] = {-1e30f, -1e30f, -1e30f, -1e30f};
    float l_i[4] = {0.f, 0.f, 0.f, 0.f};

    for (int kb = 0; kb <= qb; ++kb) {
        __syncthreads();   // prior-iter Ks/Vt readers done (also covers Q-frag reads)
        // ---- stage K hi/lo + V^T for this tile ----
        #pragma unroll
        for (int i = 0; i < 4; ++i) {
            const int idx = i * 256 + tid;
            const int rr  = idx >> 4;
            const int c4  = (idx & 15) * 4;
            const size_t off = (size_t)(kb * 64 + rr) * rs + c4;
            const float4 kv = *reinterpret_cast<const float4*>(&kbase[off]);
            const float kf[4] = {kv.x, kv.y, kv.z, kv.w};
            u16x4 hi, lo;
            #pragma unroll
            for (int j = 0; j < 4; ++j) {
                const unsigned short hu = f32_bf16(kf[j]);
                hi[j] = hu;
                lo[j] = f32_bf16(kf[j] - bf16_f32(hu));
            }
            *reinterpret_cast<u16x4*>(&Ksh[rr][c4]) = hi;
            *reinterpret_cast<u16x4*>(&Ksl[rr][c4]) = lo;
            const float4 vv = *reinterpret_cast<const float4*>(&vbase[off]);
            Vt[c4 + 0][rr] = f32_bf16(vv.x);
            Vt[c4 + 1][rr] = f32_bf16(vv.y);
            Vt[c4 + 2][rr] = f32_bf16(vv.z);
            Vt[c4 + 3][rr] = f32_bf16(vv.w);
        }
        __syncthreads();

        // ---- S = Q K^T (3-term hi/lo), 4 col-tiles x 2 d-steps ----
        f32x4 sacc[4];
        #pragma unroll
        for (int t = 0; t < 4; ++t) sacc[t] = zero4;
        #pragma unroll
        for (int tc = 0; tc < 4; ++tc) {
            #pragma unroll
            for (int d = 0; d < 2; ++d) {
                const bf16x8 kh = *reinterpret_cast<const bf16x8*>(&Ksh[tc * 16 + lc][d * 32 + lg * 8]);
                const bf16x8 kl = *reinterpret_cast<const bf16x8*>(&Ksl[tc * 16 + lc][d * 32 + lg * 8]);
                sacc[tc] = mfma16(qh[d], kh, sacc[tc]);
                sacc[tc] = mfma16(ql[d], kh, sacc[tc]);
                sacc[tc] = mfma16(qh[d], kl, sacc[tc]);
            }
        }

        // ---- mask + online softmax (fp32) ----
        const bool diag = (kb == qb);
        float sv[4][4];
        #pragma unroll
        for (int tc = 0; tc < 4; ++tc)
            #pragma unroll
            for (int i = 0; i < 4; ++i) {
                float v = sacc[tc][i] * 8.0f;
                if (diag && (tc * 16 + lc) > (wave * 16 + lg * 4 + i)) v = -1e30f;
                sv[tc][i] = v;
            }
        #pragma unroll
        for (int i = 0; i < 4; ++i) {
            float mx = fmaxf(fmaxf(sv[0][i], sv[1][i]), fmaxf(sv[2][i], sv[3][i]));
            mx = fmaxf(mx, __shfl_xor(mx, 1));
            mx = fmaxf(mx, __shfl_xor(mx, 2));
            mx = fmaxf(mx, __shfl_xor(mx, 4));
            mx = fmaxf(mx, __shfl_xor(mx, 8));
            const float mnew = fmaxf(m_i[i], mx);
            const float corr = __expf(m_i[i] - mnew);
            float psum = 0.f;
            #pragma unroll
            for (int tc = 0; tc < 4; ++tc) {
                const float p = __expf(sv[tc][i] - mnew);
                sv[tc][i] = p;
                psum += p;
            }
            psum += __shfl_xor(psum, 1);
            psum += __shfl_xor(psum, 2);
            psum += __shfl_xor(psum, 4);
            psum += __shfl_xor(psum, 8);
            l_i[i] = l_i[i] * corr + psum;
            m_i[i] = mnew;
            #pragma unroll
            for (int t = 0; t < 4; ++t) yacc[t][i] *= corr;
        }

        // ---- P -> LDS (bf16, wave-private: no barrier needed) ----
        #pragma unroll
        for (int tc = 0; tc < 4; ++tc)
            #pragma unroll
            for (int i = 0; i < 4; ++i)
                Ps[wave][lg * 4 + i][tc * 16 + lc] = f32_bf16(sv[tc][i]);

        // ---- y += P V ----
        bf16x8 pa[2];
        #pragma unroll
        for (int ks = 0; ks < 2; ++ks)
            pa[ks] = *reinterpret_cast<const bf16x8*>(&Ps[wave][lc][ks * 32 + lg * 8]);
        #pragma unroll
        for (int t = 0; t < 4; ++t) {
            #pragma unroll
            for (int ks = 0; ks < 2; ++ks) {
                const bf16x8 vb = *reinterpret_cast<const bf16x8*>(&Vt[t * 16 + lc][ks * 32 + lg * 8]);
                yacc[t] = mfma16(pa[ks], vb, yacc[t]);
            }
        }
    }

    // ---- epilogue ----
    float inv[4];
    #pragma unroll
    for (int i = 0; i < 4; ++i) inv[i] = 1.0f / l_i[i];
    float* yrow0 = y + (size_t)(b * CTXLEN + qb * 64 + wave * 16 + lg * 4) * DMODEL + h * HDIM;
    #pragma unroll
    for (int t = 0; t < 4; ++t)
        #pragma unroll
        for (int i = 0; i < 4; ++i)
            yrow0[(size_t)i * DMODEL + t * 16 + lc] = yacc[t][i] * inv[i];
}

// ---------------------------------------------------------------------------
extern "C" void kernel_launch(void* const* d_in, const int* in_sizes, int n_in,
                              void* d_out, int out_size, void* d_ws, size_t ws_size,
                              hipStream_t stream) {
    const float* x      = (const float*)d_in[0];
    const float* w_qkv  = (const float*)d_in[1];
    const float* w_proj = (const float*)d_in[2];
    const float* b_proj = (const float*)d_in[3];
    float* out = (float*)d_out;

    float* qkv = (float*)d_ws;                              // [4096, 3072]
    float* y   = qkv + (size_t)M_TOTAL * 3 * DMODEL;        // [4096, 1024]

    const dim3 blk(256);

    gemm_nt_f32<<<dim3(3 * DMODEL / 64, M_TOTAL / 64), blk, 0, stream>>>(
        x, w_qkv, nullptr, qkv, M_TOTAL, 3 * DMODEL, DMODEL);

    attn_fwd_mfma<<<dim3(CTXLEN / 64, BATCH * NHEAD), blk, 0, stream>>>(qkv, y);

    gemm_nt_f32<<<dim3(DMODEL / 64, M_TOTAL / 64), blk, 0, stream>>>(
        y, w_proj, b_proj, out, M_TOTAL, DMODEL, DMODEL);
}

// Round 3
// 320.816 us; speedup vs baseline: 5.3277x; 2.1105x over previous
//
#include <hip/hip_runtime.h>
#include <hip/hip_bf16.h>

#define DMODEL 1024
#define NHEAD 16
#define HDIM 64
#define CTXLEN 2048
#define BATCH 2
#define M_TOTAL (BATCH * CTXLEN)   // 4096

typedef unsigned short ushort_t;
typedef __attribute__((ext_vector_type(8))) short bf16x8;
typedef __attribute__((ext_vector_type(4))) float f32x4;
typedef __attribute__((ext_vector_type(4))) unsigned short u16x4;

__device__ __forceinline__ unsigned short f32_bf16(float f) {
    unsigned u = __builtin_bit_cast(unsigned, f);
    u += 0x7FFFu + ((u >> 16) & 1u);
    return (unsigned short)(u >> 16);
}
__device__ __forceinline__ float bf16_f32(unsigned short h) {
    unsigned u = ((unsigned)h) << 16;
    return __builtin_bit_cast(float, u);
}
__device__ __forceinline__ f32x4 mfma16(bf16x8 a, bf16x8 b, f32x4 c) {
    return __builtin_amdgcn_mfma_f32_16x16x32_bf16(a, b, c, 0, 0, 0);
}
__device__ __forceinline__ void gload_lds16(const ushort_t* g, ushort_t* l) {
    __builtin_amdgcn_global_load_lds(
        (const __attribute__((address_space(1))) void*)g,
        (__attribute__((address_space(3))) void*)l, 16, 0, 0);
}

// ---------------------------------------------------------------------------
// Elementwise converts
// ---------------------------------------------------------------------------
__global__ __launch_bounds__(256)
void split_hilo_f32(const float* __restrict__ src, ushort_t* __restrict__ h,
                    ushort_t* __restrict__ l, int n4) {
    for (int i = blockIdx.x * blockDim.x + threadIdx.x; i < n4;
         i += gridDim.x * blockDim.x) {
        const float4 v = reinterpret_cast<const float4*>(src)[i];
        const float f[4] = {v.x, v.y, v.z, v.w};
        u16x4 hi, lo;
        #pragma unroll
        for (int j = 0; j < 4; ++j) {
            const unsigned short hu = f32_bf16(f[j]);
            hi[j] = hu;
            lo[j] = f32_bf16(f[j] - bf16_f32(hu));
        }
        reinterpret_cast<u16x4*>(h)[i] = hi;
        reinterpret_cast<u16x4*>(l)[i] = lo;
    }
}

__global__ __launch_bounds__(256)
void conv_f32_bf16(const float* __restrict__ src, ushort_t* __restrict__ dst, int n4) {
    for (int i = blockIdx.x * blockDim.x + threadIdx.x; i < n4;
         i += gridDim.x * blockDim.x) {
        const float4 v = reinterpret_cast<const float4*>(src)[i];
        u16x4 o;
        o[0] = f32_bf16(v.x); o[1] = f32_bf16(v.y);
        o[2] = f32_bf16(v.z); o[3] = f32_bf16(v.w);
        reinterpret_cast<u16x4*>(dst)[i] = o;
    }
}

// ---------------------------------------------------------------------------
// bf16 MFMA GEMM (NT): C[M,N] = A·B^T (+bias). A[M,K], B[N,K] bf16 (row-major,
// K contiguous). SPLIT=1: A≈Ah+Al, B≈Bh+Bl, 3-term product for near-fp32
// precision. 128x128 tile, BK=32, 256 thr = 4 waves (2x2), 4x4 16x16 frags.
// LDS: linear dest for global_load_lds; XOR slot swizzle (slot = lg ^
// ((row>>1)&3)) applied on the pre-swizzled GLOBAL source + the frag read
// address -> <=2-way bank conflicts (free).
// ---------------------------------------------------------------------------
template<bool SPLIT>
__global__ __launch_bounds__(256)
void gemm_bf16_nt(const ushort_t* __restrict__ Ah, const ushort_t* __restrict__ Al,
                  const ushort_t* __restrict__ Bh, const ushort_t* __restrict__ Bl,
                  const float* __restrict__ bias, float* __restrict__ C,
                  int M, int N, int K) {
    constexpr int NB = SPLIT ? 4 : 2;
    constexpr int IAH = 0, IAL = 1, IBH = SPLIT ? 2 : 1, IBL = 3;
    __shared__ ushort_t lds[NB * 4096];   // per tile: 128 rows x 32 bf16 (64B)

    const int tid  = threadIdx.x;
    const int lane = tid & 63;
    const int wave = tid >> 6;
    const int lc   = lane & 15;
    const int lg   = lane >> 4;
    const int wr   = wave >> 1;
    const int wc   = wave & 1;
    const int row0 = blockIdx.y * 128;
    const int col0 = blockIdx.x * 128;

    // --- staging: chunk c covers LDS bytes c*16 (linear); logical (row, slot l)
    // with l = (c&3) ^ sw(row), sw(row) = (row>>1)&3 = (c>>3)&3.
    const int c0 = tid, c1 = 256 + tid;
    const int r0 = c0 >> 2, l0 = (c0 & 3) ^ ((c0 >> 3) & 3);
    const int r1 = c1 >> 2, l1 = (c1 & 3) ^ ((c1 >> 3) & 3);
    const size_t gaoff0 = (size_t)(row0 + r0) * K + l0 * 8;
    const size_t gaoff1 = (size_t)(row0 + r1) * K + l1 * 8;
    const size_t gboff0 = (size_t)(col0 + r0) * K + l0 * 8;
    const size_t gboff1 = (size_t)(col0 + r1) * K + l1 * 8;
    const int ld0 = c0 * 8, ld1 = c1 * 8;   // ushort offsets within a tile

    // --- frag read offsets (per-lane constant, swizzled)
    int aoff[4], boff[4];
    #pragma unroll
    for (int m = 0; m < 4; ++m) {
        const int ra = wr * 64 + m * 16 + lc;
        aoff[m] = ra * 32 + ((lg ^ ((ra >> 1) & 3)) * 8);
        const int rb = wc * 64 + m * 16 + lc;
        boff[m] = rb * 32 + ((lg ^ ((rb >> 1) & 3)) * 8);
    }

    f32x4 acc[4][4];
    const f32x4 zero4 = {0.f, 0.f, 0.f, 0.f};
    #pragma unroll
    for (int m = 0; m < 4; ++m)
        #pragma unroll
        for (int n = 0; n < 4; ++n) acc[m][n] = zero4;

    const int NT = K >> 5;

    auto stage = [&](int kt) {
        const int ko = kt * 32;
        gload_lds16(Ah + gaoff0 + ko, &lds[IAH * 4096 + ld0]);
        gload_lds16(Ah + gaoff1 + ko, &lds[IAH * 4096 + ld1]);
        if (SPLIT) {
            gload_lds16(Al + gaoff0 + ko, &lds[IAL * 4096 + ld0]);
            gload_lds16(Al + gaoff1 + ko, &lds[IAL * 4096 + ld1]);
        }
        gload_lds16(Bh + gboff0 + ko, &lds[IBH * 4096 + ld0]);
        gload_lds16(Bh + gboff1 + ko, &lds[IBH * 4096 + ld1]);
        if (SPLIT) {
            gload_lds16(Bl + gboff0 + ko, &lds[IBL * 4096 + ld0]);
            gload_lds16(Bl + gboff1 + ko, &lds[IBL * 4096 + ld1]);
        }
    };

    stage(0);
    for (int kt = 0; kt < NT; ++kt) {
        __syncthreads();   // tile kt staged (vmcnt drained by compiler)
        bf16x8 fah[4], fbh[4], fal[4], fbl[4];
        #pragma unroll
        for (int m = 0; m < 4; ++m) {
            fah[m] = *reinterpret_cast<const bf16x8*>(&lds[IAH * 4096 + aoff[m]]);
            fbh[m] = *reinterpret_cast<const bf16x8*>(&lds[IBH * 4096 + boff[m]]);
            if (SPLIT) {
                fal[m] = *reinterpret_cast<const bf16x8*>(&lds[IAL * 4096 + aoff[m]]);
                fbl[m] = *reinterpret_cast<const bf16x8*>(&lds[IBL * 4096 + boff[m]]);
            }
        }
        __syncthreads();   // all waves' frag reads done -> LDS reusable
        if (kt + 1 < NT) stage(kt + 1);   // DMA overlaps MFMAs below
        #pragma unroll
        for (int m = 0; m < 4; ++m)
            #pragma unroll
            for (int n = 0; n < 4; ++n) {
                f32x4 t = acc[m][n];
                t = mfma16(fah[m], fbh[n], t);
                if (SPLIT) {
                    t = mfma16(fal[m], fbh[n], t);
                    t = mfma16(fah[m], fbl[n], t);
                }
                acc[m][n] = t;
            }
    }

    // epilogue: D col=lane&15, row=(lane>>4)*4+i
    #pragma unroll
    for (int m = 0; m < 4; ++m)
        #pragma unroll
        for (int i = 0; i < 4; ++i) {
            const int r = row0 + wr * 64 + m * 16 + lg * 4 + i;
            #pragma unroll
            for (int n = 0; n < 4; ++n) {
                const int c = col0 + wc * 64 + n * 16 + lc;
                float v = acc[m][n][i];
                if (bias) v += bias[c];
                C[(size_t)r * N + c] = v;
            }
        }
}

// ---------------------------------------------------------------------------
// Flash causal attention, bf16 MFMA (hi/lo split QK^T). Unchanged from R1
// except: output y written as bf16 (feeds proj GEMM A-operand directly).
// ---------------------------------------------------------------------------
#define LDSS 72

__global__ __launch_bounds__(256)
void attn_fwd_mfma(const float* __restrict__ qkv, ushort_t* __restrict__ yb) {
    __shared__ __align__(16) unsigned short Ksh[64][LDSS];
    __shared__ __align__(16) unsigned short Ksl[64][LDSS];
    __shared__ __align__(16) unsigned short Vt [64][LDSS];
    __shared__ __align__(16) unsigned short Ps [4][16][LDSS];

    const int qb = (int)gridDim.x - 1 - (int)blockIdx.x;
    const int bh = blockIdx.y;
    const int b  = bh >> 4;
    const int h  = bh & 15;

    const int tid  = threadIdx.x;
    const int wave = tid >> 6;
    const int lane = tid & 63;
    const int lc   = lane & 15;
    const int lg   = lane >> 4;

    const size_t rs = 3 * DMODEL;
    const float* qbase = qkv + (size_t)b * CTXLEN * rs + h * HDIM;
    const float* kbase = qbase + DMODEL;
    const float* vbase = qbase + 2 * DMODEL;

    #pragma unroll
    for (int i = 0; i < 4; ++i) {
        const int idx = i * 256 + tid;
        const int rr  = idx >> 4;
        const int c4  = (idx & 15) * 4;
        const float4 v = *reinterpret_cast<const float4*>(
            &qbase[(size_t)(qb * 64 + rr) * rs + c4]);
        const float f[4] = {v.x, v.y, v.z, v.w};
        u16x4 hi, lo;
        #pragma unroll
        for (int j = 0; j < 4; ++j) {
            const unsigned short hu = f32_bf16(f[j]);
            hi[j] = hu;
            lo[j] = f32_bf16(f[j] - bf16_f32(hu));
        }
        *reinterpret_cast<u16x4*>(&Ksh[rr][c4]) = hi;
        *reinterpret_cast<u16x4*>(&Ksl[rr][c4]) = lo;
    }
    __syncthreads();
    bf16x8 qh[2], ql[2];
    #pragma unroll
    for (int d = 0; d < 2; ++d) {
        qh[d] = *reinterpret_cast<const bf16x8*>(&Ksh[wave * 16 + lc][d * 32 + lg * 8]);
        ql[d] = *reinterpret_cast<const bf16x8*>(&Ksl[wave * 16 + lc][d * 32 + lg * 8]);
    }

    const f32x4 zero4 = {0.f, 0.f, 0.f, 0.f};
    f32x4 yacc[4];
    #pragma unroll
    for (int t = 0; t < 4; ++t) yacc[t] = zero4;
    float m_i[4] = {-1e30f, -1e30f, -1e30f, -1e30f};
    float l_i[4] = {0.f, 0.f, 0.f, 0.f};

    for (int kb = 0; kb <= qb; ++kb) {
        __syncthreads();
        #pragma unroll
        for (int i = 0; i < 4; ++i) {
            const int idx = i * 256 + tid;
            const int rr  = idx >> 4;
            const int c4  = (idx & 15) * 4;
            const size_t off = (size_t)(kb * 64 + rr) * rs + c4;
            const float4 kv = *reinterpret_cast<const float4*>(&kbase[off]);
            const float kf[4] = {kv.x, kv.y, kv.z, kv.w};
            u16x4 hi, lo;
            #pragma unroll
            for (int j = 0; j < 4; ++j) {
                const unsigned short hu = f32_bf16(kf[j]);
                hi[j] = hu;
                lo[j] = f32_bf16(kf[j] - bf16_f32(hu));
            }
            *reinterpret_cast<u16x4*>(&Ksh[rr][c4]) = hi;
            *reinterpret_cast<u16x4*>(&Ksl[rr][c4]) = lo;
            const float4 vv = *reinterpret_cast<const float4*>(&vbase[off]);
            Vt[c4 + 0][rr] = f32_bf16(vv.x);
            Vt[c4 + 1][rr] = f32_bf16(vv.y);
            Vt[c4 + 2][rr] = f32_bf16(vv.z);
            Vt[c4 + 3][rr] = f32_bf16(vv.w);
        }
        __syncthreads();

        f32x4 sacc[4];
        #pragma unroll
        for (int t = 0; t < 4; ++t) sacc[t] = zero4;
        #pragma unroll
        for (int tc = 0; tc < 4; ++tc) {
            #pragma unroll
            for (int d = 0; d < 2; ++d) {
                const bf16x8 kh = *reinterpret_cast<const bf16x8*>(&Ksh[tc * 16 + lc][d * 32 + lg * 8]);
                const bf16x8 kl = *reinterpret_cast<const bf16x8*>(&Ksl[tc * 16 + lc][d * 32 + lg * 8]);
                sacc[tc] = mfma16(qh[d], kh, sacc[tc]);
                sacc[tc] = mfma16(ql[d], kh, sacc[tc]);
                sacc[tc] = mfma16(qh[d], kl, sacc[tc]);
            }
        }

        const bool diag = (kb == qb);
        float sv[4][4];
        #pragma unroll
        for (int tc = 0; tc < 4; ++tc)
            #pragma unroll
            for (int i = 0; i < 4; ++i) {
                float v = sacc[tc][i] * 8.0f;
                if (diag && (tc * 16 + lc) > (wave * 16 + lg * 4 + i)) v = -1e30f;
                sv[tc][i] = v;
            }
        #pragma unroll
        for (int i = 0; i < 4; ++i) {
            float mx = fmaxf(fmaxf(sv[0][i], sv[1][i]), fmaxf(sv[2][i], sv[3][i]));
            mx = fmaxf(mx, __shfl_xor(mx, 1));
            mx = fmaxf(mx, __shfl_xor(mx, 2));
            mx = fmaxf(mx, __shfl_xor(mx, 4));
            mx = fmaxf(mx, __shfl_xor(mx, 8));
            const float mnew = fmaxf(m_i[i], mx);
            const float corr = __expf(m_i[i] - mnew);
            float psum = 0.f;
            #pragma unroll
            for (int tc = 0; tc < 4; ++tc) {
                const float p = __expf(sv[tc][i] - mnew);
                sv[tc][i] = p;
                psum += p;
            }
            psum += __shfl_xor(psum, 1);
            psum += __shfl_xor(psum, 2);
            psum += __shfl_xor(psum, 4);
            psum += __shfl_xor(psum, 8);
            l_i[i] = l_i[i] * corr + psum;
            m_i[i] = mnew;
            #pragma unroll
            for (int t = 0; t < 4; ++t) yacc[t][i] *= corr;
        }

        #pragma unroll
        for (int tc = 0; tc < 4; ++tc)
            #pragma unroll
            for (int i = 0; i < 4; ++i)
                Ps[wave][lg * 4 + i][tc * 16 + lc] = f32_bf16(sv[tc][i]);

        bf16x8 pa[2];
        #pragma unroll
        for (int ks = 0; ks < 2; ++ks)
            pa[ks] = *reinterpret_cast<const bf16x8*>(&Ps[wave][lc][ks * 32 + lg * 8]);
        #pragma unroll
        for (int t = 0; t < 4; ++t) {
            #pragma unroll
            for (int ks = 0; ks < 2; ++ks) {
                const bf16x8 vb = *reinterpret_cast<const bf16x8*>(&Vt[t * 16 + lc][ks * 32 + lg * 8]);
                yacc[t] = mfma16(pa[ks], vb, yacc[t]);
            }
        }
    }

    float inv[4];
    #pragma unroll
    for (int i = 0; i < 4; ++i) inv[i] = 1.0f / l_i[i];
    ushort_t* yrow0 = yb + (size_t)(b * CTXLEN + qb * 64 + wave * 16 + lg * 4) * DMODEL + h * HDIM;
    #pragma unroll
    for (int t = 0; t < 4; ++t)
        #pragma unroll
        for (int i = 0; i < 4; ++i)
            yrow0[(size_t)i * DMODEL + t * 16 + lc] = f32_bf16(yacc[t][i] * inv[i]);
}

// ---------------------------------------------------------------------------
extern "C" void kernel_launch(void* const* d_in, const int* in_sizes, int n_in,
                              void* d_out, int out_size, void* d_ws, size_t ws_size,
                              hipStream_t stream) {
    const float* x      = (const float*)d_in[0];   // [4096, 1024]
    const float* w_qkv  = (const float*)d_in[1];   // [3072, 1024]
    const float* w_proj = (const float*)d_in[2];   // [1024, 1024]
    const float* b_proj = (const float*)d_in[3];   // [1024]
    float* out = (float*)d_out;

    // ws layout (bytes):
    //   qkv fp32 [4096,3072]                     @ 0         (50,331,648)
    //   wh bf16  [3072,1024]                     @ 50331648  ( 6,291,456)
    //   wl bf16  [3072,1024]                     @ 56623104  ( 6,291,456)
    //   xh bf16  [4096,1024] | yb bf16 (reuse)   @ 62914560  ( 8,388,608)
    //   xl bf16  [4096,1024] | wph bf16 (reuse)  @ 71303168  ( 8,388,608)
    char* ws = (char*)d_ws;
    float*    qkv = (float*)(ws);
    ushort_t* wh  = (ushort_t*)(ws + 50331648);
    ushort_t* wl  = (ushort_t*)(ws + 56623104);
    ushort_t* xh  = (ushort_t*)(ws + 62914560);
    ushort_t* xl  = (ushort_t*)(ws + 71303168);
    ushort_t* yb  = xh;    // reused after qkv GEMM consumed xh/xl
    ushort_t* wph = xl;

    const dim3 blk(256);

    // 1) split x and w_qkv into bf16 hi/lo
    split_hilo_f32<<<dim3(2048), blk, 0, stream>>>(x, xh, xl, M_TOTAL * DMODEL / 4);
    split_hilo_f32<<<dim3(2048), blk, 0, stream>>>(w_qkv, wh, wl, 3 * DMODEL * DMODEL / 4);

    // 2) qkv = x @ w_qkv^T  (3-term hi/lo MFMA)  M=4096 N=3072 K=1024
    gemm_bf16_nt<true><<<dim3(3 * DMODEL / 128, M_TOTAL / 128), blk, 0, stream>>>(
        xh, xl, wh, wl, nullptr, qkv, M_TOTAL, 3 * DMODEL, DMODEL);

    // 3) w_proj -> bf16 (overlays xl: must follow qkv GEMM)
    conv_f32_bf16<<<dim3(1024), blk, 0, stream>>>(w_proj, wph, DMODEL * DMODEL / 4);

    // 4) attention (writes yb bf16, overlays xh)
    attn_fwd_mfma<<<dim3(CTXLEN / 64, BATCH * NHEAD), blk, 0, stream>>>(qkv, yb);

    // 5) out = y @ w_proj^T + b  (plain bf16 MFMA)  M=4096 N=1024 K=1024
    gemm_bf16_nt<false><<<dim3(DMODEL / 128, M_TOTAL / 128), blk, 0, stream>>>(
        yb, nullptr, wph, nullptr, b_proj, out, M_TOTAL, DMODEL, DMODEL);
}

// Round 5
// 193.114 us; speedup vs baseline: 8.8508x; 1.6613x over previous
//
#include <hip/hip_runtime.h>
#include <hip/hip_bf16.h>

#define DMODEL 1024
#define NHEAD 16
#define HDIM 64
#define CTXLEN 2048
#define BATCH 2
#define M_TOTAL (BATCH * CTXLEN)   // 4096

typedef unsigned short ushort_t;
typedef __attribute__((ext_vector_type(8))) short bf16x8;
typedef __attribute__((ext_vector_type(8))) unsigned short u16x8;
typedef __attribute__((ext_vector_type(4))) float f32x4;
typedef __attribute__((ext_vector_type(4))) unsigned short u16x4;

__device__ __forceinline__ unsigned short f32_bf16(float f) {
    unsigned u = __builtin_bit_cast(unsigned, f);
    u += 0x7FFFu + ((u >> 16) & 1u);
    return (unsigned short)(u >> 16);
}
__device__ __forceinline__ float bf16_f32(unsigned short h) {
    unsigned u = ((unsigned)h) << 16;
    return __builtin_bit_cast(float, u);
}
__device__ __forceinline__ float fast_exp2(float x) {
    return __builtin_amdgcn_exp2f(x);   // v_exp_f32 (native base-2)
}
__device__ __forceinline__ f32x4 mfma16(bf16x8 a, bf16x8 b, f32x4 c) {
    return __builtin_amdgcn_mfma_f32_16x16x32_bf16(a, b, c, 0, 0, 0);
}
__device__ __forceinline__ void gload_lds16(const ushort_t* g, ushort_t* l) {
    __builtin_amdgcn_global_load_lds(
        (const __attribute__((address_space(1))) void*)g,
        (__attribute__((address_space(3))) void*)l, 16, 0, 0);
}

// ---------------------------------------------------------------------------
// Elementwise converts (GEMM input prep)
// ---------------------------------------------------------------------------
__global__ __launch_bounds__(256)
void split_hilo_f32(const float* __restrict__ src, ushort_t* __restrict__ h,
                    ushort_t* __restrict__ l, int n4) {
    for (int i = blockIdx.x * blockDim.x + threadIdx.x; i < n4;
         i += gridDim.x * blockDim.x) {
        const float4 v = reinterpret_cast<const float4*>(src)[i];
        const float f[4] = {v.x, v.y, v.z, v.w};
        u16x4 hi, lo;
        #pragma unroll
        for (int j = 0; j < 4; ++j) {
            const unsigned short hu = f32_bf16(f[j]);
            hi[j] = hu;
            lo[j] = f32_bf16(f[j] - bf16_f32(hu));
        }
        reinterpret_cast<u16x4*>(h)[i] = hi;
        reinterpret_cast<u16x4*>(l)[i] = lo;
    }
}

__global__ __launch_bounds__(256)
void conv_f32_bf16(const float* __restrict__ src, ushort_t* __restrict__ dst, int n4) {
    for (int i = blockIdx.x * blockDim.x + threadIdx.x; i < n4;
         i += gridDim.x * blockDim.x) {
        const float4 v = reinterpret_cast<const float4*>(src)[i];
        u16x4 o;
        o[0] = f32_bf16(v.x); o[1] = f32_bf16(v.y);
        o[2] = f32_bf16(v.z); o[3] = f32_bf16(v.w);
        reinterpret_cast<u16x4*>(dst)[i] = o;
    }
}

// ---------------------------------------------------------------------------
// bf16 MFMA GEMM (NT), 128x128 tile, BK=32, 4 waves.
// MODE 0: plain bf16 inputs, fp32 C + bias (proj GEMM).
// MODE 1: hi/lo split inputs (3-term), epilogue writes attention-ready arrays:
//   sec 0 (cols 0-1023):    qh/ql [bh][t][64] bf16 hi/lo
//   sec 1 (cols 1024-2047): kh/kl [bh][t][64] bf16 hi/lo
//   sec 2 (cols 2048-3071): vb    [bh][t][64] bf16
// ---------------------------------------------------------------------------
template<int MODE>
__global__ __launch_bounds__(256)
void gemm_bf16_nt(const ushort_t* __restrict__ Ah, const ushort_t* __restrict__ Al,
                  const ushort_t* __restrict__ Bh, const ushort_t* __restrict__ Bl,
                  const float* __restrict__ bias, float* __restrict__ C,
                  ushort_t* __restrict__ qh, ushort_t* __restrict__ ql,
                  ushort_t* __restrict__ kh, ushort_t* __restrict__ kl,
                  ushort_t* __restrict__ vb,
                  int M, int N, int K) {
    constexpr bool SPLIT = (MODE == 1);
    constexpr int NB = SPLIT ? 4 : 2;
    constexpr int IAH = 0, IAL = 1, IBH = SPLIT ? 2 : 1, IBL = 3;
    __shared__ ushort_t lds[NB * 4096];

    const int tid  = threadIdx.x;
    const int lane = tid & 63;
    const int wave = tid >> 6;
    const int lc   = lane & 15;
    const int lg   = lane >> 4;
    const int wr   = wave >> 1;
    const int wc   = wave & 1;
    const int row0 = blockIdx.y * 128;
    const int col0 = blockIdx.x * 128;

    const int c0 = tid, c1 = 256 + tid;
    const int r0 = c0 >> 2, l0 = (c0 & 3) ^ ((c0 >> 3) & 3);
    const int r1 = c1 >> 2, l1 = (c1 & 3) ^ ((c1 >> 3) & 3);
    const size_t gaoff0 = (size_t)(row0 + r0) * K + l0 * 8;
    const size_t gaoff1 = (size_t)(row0 + r1) * K + l1 * 8;
    const size_t gboff0 = (size_t)(col0 + r0) * K + l0 * 8;
    const size_t gboff1 = (size_t)(col0 + r1) * K + l1 * 8;
    const int ld0 = c0 * 8, ld1 = c1 * 8;

    int aoff[4], boff[4];
    #pragma unroll
    for (int m = 0; m < 4; ++m) {
        const int ra = wr * 64 + m * 16 + lc;
        aoff[m] = ra * 32 + ((lg ^ ((ra >> 1) & 3)) * 8);
        const int rb = wc * 64 + m * 16 + lc;
        boff[m] = rb * 32 + ((lg ^ ((rb >> 1) & 3)) * 8);
    }

    f32x4 acc[4][4];
    const f32x4 zero4 = {0.f, 0.f, 0.f, 0.f};
    #pragma unroll
    for (int m = 0; m < 4; ++m)
        #pragma unroll
        for (int n = 0; n < 4; ++n) acc[m][n] = zero4;

    const int NT = K >> 5;

    auto stage = [&](int kt) {
        const int ko = kt * 32;
        gload_lds16(Ah + gaoff0 + ko, &lds[IAH * 4096 + ld0]);
        gload_lds16(Ah + gaoff1 + ko, &lds[IAH * 4096 + ld1]);
        if (SPLIT) {
            gload_lds16(Al + gaoff0 + ko, &lds[IAL * 4096 + ld0]);
            gload_lds16(Al + gaoff1 + ko, &lds[IAL * 4096 + ld1]);
        }
        gload_lds16(Bh + gboff0 + ko, &lds[IBH * 4096 + ld0]);
        gload_lds16(Bh + gboff1 + ko, &lds[IBH * 4096 + ld1]);
        if (SPLIT) {
            gload_lds16(Bl + gboff0 + ko, &lds[IBL * 4096 + ld0]);
            gload_lds16(Bl + gboff1 + ko, &lds[IBL * 4096 + ld1]);
        }
    };

    stage(0);
    for (int kt = 0; kt < NT; ++kt) {
        __syncthreads();
        bf16x8 fah[4], fbh[4], fal[4], fbl[4];
        #pragma unroll
        for (int m = 0; m < 4; ++m) {
            fah[m] = *reinterpret_cast<const bf16x8*>(&lds[IAH * 4096 + aoff[m]]);
            fbh[m] = *reinterpret_cast<const bf16x8*>(&lds[IBH * 4096 + boff[m]]);
            if (SPLIT) {
                fal[m] = *reinterpret_cast<const bf16x8*>(&lds[IAL * 4096 + aoff[m]]);
                fbl[m] = *reinterpret_cast<const bf16x8*>(&lds[IBL * 4096 + boff[m]]);
            }
        }
        __syncthreads();
        if (kt + 1 < NT) stage(kt + 1);
        #pragma unroll
        for (int m = 0; m < 4; ++m)
            #pragma unroll
            for (int n = 0; n < 4; ++n) {
                f32x4 t = acc[m][n];
                t = mfma16(fah[m], fbh[n], t);
                if (SPLIT) {
                    t = mfma16(fal[m], fbh[n], t);
                    t = mfma16(fah[m], fbl[n], t);
                }
                acc[m][n] = t;
            }
    }

    if (MODE == 0) {
        #pragma unroll
        for (int m = 0; m < 4; ++m)
            #pragma unroll
            for (int i = 0; i < 4; ++i) {
                const int r = row0 + wr * 64 + m * 16 + lg * 4 + i;
                #pragma unroll
                for (int n = 0; n < 4; ++n) {
                    const int c = col0 + wc * 64 + n * 16 + lc;
                    C[(size_t)r * N + c] = acc[m][n][i] + bias[c];
                }
            }
    } else {
        // whole block lies in one section (col0 is 128-aligned, sections 1024-aligned)
        const int sec = blockIdx.x >> 3;   // 0=q, 1=k, 2=v
        #pragma unroll
        for (int m = 0; m < 4; ++m)
            #pragma unroll
            for (int i = 0; i < 4; ++i) {
                const int r = row0 + wr * 64 + m * 16 + lg * 4 + i;
                const int bb = r >> 11;
                const int t  = r & 2047;
                #pragma unroll
                for (int n = 0; n < 4; ++n) {
                    const int c  = col0 + wc * 64 + n * 16 + lc;
                    const int ch = c - sec * 1024;
                    const int hh = ch >> 6;
                    const int d  = ch & 63;
                    const size_t off = (((size_t)(bb * NHEAD + hh)) * CTXLEN + t) * HDIM + d;
                    const float v = acc[m][n][i];
                    if (sec == 0) {
                        const unsigned short hu = f32_bf16(v);
                        qh[off] = hu;
                        ql[off] = f32_bf16(v - bf16_f32(hu));
                    } else if (sec == 1) {
                        const unsigned short hu = f32_bf16(v);
                        kh[off] = hu;
                        kl[off] = f32_bf16(v - bf16_f32(hu));
                    } else {
                        vb[off] = f32_bf16(v);
                    }
                }
            }
    }
}

// ---------------------------------------------------------------------------
// vb [bh][t][d] -> vt [bh][d][t] (bf16), 64x64 tiles via LDS.
// ---------------------------------------------------------------------------
__global__ __launch_bounds__(256)
void transpose_v(const ushort_t* __restrict__ vb, ushort_t* __restrict__ vt) {
    __shared__ ushort_t T[64][66];
    const int tt = blockIdx.x;   // t tile
    const int bh = blockIdx.y;
    const int tid = threadIdx.x;
    const int r  = tid >> 2;
    const int c0 = (tid & 3) * 16;

    const ushort_t* src = vb + ((size_t)bh * CTXLEN + tt * 64) * HDIM;
    #pragma unroll
    for (int half = 0; half < 2; ++half) {
        const u16x8 v = *reinterpret_cast<const u16x8*>(&src[(size_t)r * HDIM + c0 + half * 8]);
        #pragma unroll
        for (int j = 0; j < 8; ++j) T[r][c0 + half * 8 + j] = v[j];
    }
    __syncthreads();
    ushort_t* dst = vt + ((size_t)bh * HDIM + r) * CTXLEN + tt * 64 + c0;
    u16x8 o0, o1;
    #pragma unroll
    for (int j = 0; j < 8; ++j) { o0[j] = T[c0 + j][r]; o1[j] = T[c0 + 8 + j][r]; }
    *reinterpret_cast<u16x8*>(&dst[0]) = o0;
    *reinterpret_cast<u16x8*>(&dst[8]) = o1;
}

// ---------------------------------------------------------------------------
// Flash causal attention, bf16 MFMA, pre-split inputs, double-buffered
// global_load_lds staging with XOR slot swizzle (slot ^= row&7).
// Grid: 1024 linear; id -> qb = 31 - id/32 (LPT order), bh = id%32.
// Block: 256 = 4 waves; wave w owns q rows 16w..16w+15 of the 64-row tile.
// ---------------------------------------------------------------------------
#define SCALE_LOG2 11.5415603271f   // 8 * log2(e)

__global__ __launch_bounds__(256)
void attn_fwd2(const ushort_t* __restrict__ qh, const ushort_t* __restrict__ ql,
               const ushort_t* __restrict__ kh, const ushort_t* __restrict__ kl,
               const ushort_t* __restrict__ vt, ushort_t* __restrict__ yb) {
    __shared__ ushort_t KH[2][4096];
    __shared__ ushort_t KL[2][4096];
    __shared__ ushort_t VT[2][4096];
    __shared__ ushort_t Ps[4][16][72];

    const int id = blockIdx.x;
    const int bh = id & 31;
    const int qb = 31 - (id >> 5);
    const int b  = bh >> 4;

    const int tid  = threadIdx.x;
    const int wave = tid >> 6;
    const int lane = tid & 63;
    const int lc   = lane & 15;
    const int lg   = lane >> 4;

    const ushort_t* khb = kh + (size_t)bh * CTXLEN * HDIM;
    const ushort_t* klb = kl + (size_t)bh * CTXLEN * HDIM;
    const ushort_t* vtb = vt + (size_t)bh * HDIM * CTXLEN;

    // staging chunk mapping: c in [0,512): row r=c>>3, lds slot s=c&7,
    // global slot sg = s ^ (r&7). LDS dest linear (c*8 ushorts).
    const int cA = tid, cB = 256 + tid;
    const int rA = cA >> 3, sgA = (cA & 7) ^ (rA & 7);
    const int rB = cB >> 3, sgB = (cB & 7) ^ (rB & 7);

    auto stage = [&](int kb, int buf) {
        const size_t koff = (size_t)(kb * 64);
        gload_lds16(khb + (koff + rA) * HDIM + sgA * 8, &KH[buf][cA * 8]);
        gload_lds16(khb + (koff + rB) * HDIM + sgB * 8, &KH[buf][cB * 8]);
        gload_lds16(klb + (koff + rA) * HDIM + sgA * 8, &KL[buf][cA * 8]);
        gload_lds16(klb + (koff + rB) * HDIM + sgB * 8, &KL[buf][cB * 8]);
        gload_lds16(vtb + (size_t)rA * CTXLEN + kb * 64 + sgA * 8, &VT[buf][cA * 8]);
        gload_lds16(vtb + (size_t)rB * CTXLEN + kb * 64 + sgB * 8, &VT[buf][cB * 8]);
    };

    // Q fragments straight from global (bf16 hi/lo, 16B per frag)
    const size_t qrow = (size_t)bh * CTXLEN + qb * 64 + wave * 16 + lc;
    bf16x8 qfh[2], qfl[2];
    #pragma unroll
    for (int ds = 0; ds < 2; ++ds) {
        qfh[ds] = *reinterpret_cast<const bf16x8*>(&qh[qrow * HDIM + ds * 32 + lg * 8]);
        qfl[ds] = *reinterpret_cast<const bf16x8*>(&ql[qrow * HDIM + ds * 32 + lg * 8]);
    }

    const f32x4 zero4 = {0.f, 0.f, 0.f, 0.f};
    f32x4 yacc[4];
    #pragma unroll
    for (int t = 0; t < 4; ++t) yacc[t] = zero4;
    float m_i[4] = {-1e30f, -1e30f, -1e30f, -1e30f};
    float l_i[4] = {0.f, 0.f, 0.f, 0.f};

    stage(0, 0);
    __syncthreads();

    int cur = 0;
    for (int kb = 0; kb <= qb; ++kb) {
        if (kb < qb) stage(kb + 1, cur ^ 1);

        // ---- K fragments (swizzled reads) ----
        bf16x8 kfh[4][2], kfl[4][2];
        #pragma unroll
        for (int tc = 0; tc < 4; ++tc) {
            const int rk = tc * 16 + lc;
            #pragma unroll
            for (int ds = 0; ds < 2; ++ds) {
                const int a = rk * 64 + (((ds * 4 + lg) ^ (rk & 7)) * 8);
                kfh[tc][ds] = *reinterpret_cast<const bf16x8*>(&KH[cur][a]);
                kfl[tc][ds] = *reinterpret_cast<const bf16x8*>(&KL[cur][a]);
            }
        }

        // ---- S = Q K^T (3-term hi/lo) ----
        f32x4 sacc[4];
        #pragma unroll
        for (int t = 0; t < 4; ++t) sacc[t] = zero4;
        #pragma unroll
        for (int tc = 0; tc < 4; ++tc)
            #pragma unroll
            for (int ds = 0; ds < 2; ++ds) {
                sacc[tc] = mfma16(qfh[ds], kfh[tc][ds], sacc[tc]);
                sacc[tc] = mfma16(qfl[ds], kfh[tc][ds], sacc[tc]);
                sacc[tc] = mfma16(qfh[ds], kfl[tc][ds], sacc[tc]);
            }

        // ---- mask + online softmax (base-2 domain) ----
        const bool diag = (kb == qb);
        float sv[4][4];
        #pragma unroll
        for (int tc = 0; tc < 4; ++tc)
            #pragma unroll
            for (int i = 0; i < 4; ++i) {
                float u = sacc[tc][i] * SCALE_LOG2;
                if (diag && (tc * 16 + lc) > (wave * 16 + lg * 4 + i)) u = -1e30f;
                sv[tc][i] = u;
            }
        #pragma unroll
        for (int i = 0; i < 4; ++i) {
            float mx = fmaxf(fmaxf(sv[0][i], sv[1][i]), fmaxf(sv[2][i], sv[3][i]));
            mx = fmaxf(mx, __shfl_xor(mx, 1));
            mx = fmaxf(mx, __shfl_xor(mx, 2));
            mx = fmaxf(mx, __shfl_xor(mx, 4));
            mx = fmaxf(mx, __shfl_xor(mx, 8));
            const float mnew = fmaxf(m_i[i], mx);
            const float corr = fast_exp2(m_i[i] - mnew);
            float psum = 0.f;
            #pragma unroll
            for (int tc = 0; tc < 4; ++tc) {
                const float p = fast_exp2(sv[tc][i] - mnew);
                sv[tc][i] = p;
                psum += p;
            }
            psum += __shfl_xor(psum, 1);
            psum += __shfl_xor(psum, 2);
            psum += __shfl_xor(psum, 4);
            psum += __shfl_xor(psum, 8);
            l_i[i] = l_i[i] * corr + psum;
            m_i[i] = mnew;
            #pragma unroll
            for (int t = 0; t < 4; ++t) yacc[t][i] *= corr;
        }

        // ---- P -> LDS (wave-private) ----
        #pragma unroll
        for (int tc = 0; tc < 4; ++tc)
            #pragma unroll
            for (int i = 0; i < 4; ++i)
                Ps[wave][lg * 4 + i][tc * 16 + lc] = f32_bf16(sv[tc][i]);

        // ---- y += P V ----
        bf16x8 pa[2];
        #pragma unroll
        for (int ks = 0; ks < 2; ++ks)
            pa[ks] = *reinterpret_cast<const bf16x8*>(&Ps[wave][lc][ks * 32 + lg * 8]);
        #pragma unroll
        for (int t = 0; t < 4; ++t) {
            const int rv = t * 16 + lc;
            #pragma unroll
            for (int ks = 0; ks < 2; ++ks) {
                const int a = rv * 64 + (((ks * 4 + lg) ^ (rv & 7)) * 8);
                const bf16x8 vf = *reinterpret_cast<const bf16x8*>(&VT[cur][a]);
                yacc[t] = mfma16(pa[ks], vf, yacc[t]);
            }
        }

        __syncthreads();
        cur ^= 1;
    }

    float inv[4];
    #pragma unroll
    for (int i = 0; i < 4; ++i) inv[i] = 1.0f / l_i[i];
    ushort_t* yrow0 = yb + (size_t)(b * CTXLEN + qb * 64 + wave * 16 + lg * 4) * DMODEL
                      + (bh & 15) * HDIM;
    #pragma unroll
    for (int t = 0; t < 4; ++t)
        #pragma unroll
        for (int i = 0; i < 4; ++i)
            yrow0[(size_t)i * DMODEL + t * 16 + lc] = f32_bf16(yacc[t][i] * inv[i]);
}

// ---------------------------------------------------------------------------
extern "C" void kernel_launch(void* const* d_in, const int* in_sizes, int n_in,
                              void* d_out, int out_size, void* d_ws, size_t ws_size,
                              hipStream_t stream) {
    const float* x      = (const float*)d_in[0];
    const float* w_qkv  = (const float*)d_in[1];
    const float* w_proj = (const float*)d_in[2];
    const float* b_proj = (const float*)d_in[3];
    float* out = (float*)d_out;

    // ws layout (bytes):
    //   wh  bf16 [3072,1024]                  @ 0         ( 6,291,456)
    //   wl  bf16 [3072,1024]                  @ 6291456   ( 6,291,456)
    //   xh  bf16 [4096,1024] | yb (reuse)     @ 12582912  ( 8,388,608)
    //   xl  bf16 [4096,1024] | wph (reuse)    @ 20971520  ( 8,388,608)
    //   qh  bf16 [32][2048][64]               @ 29360128  ( 8,388,608)
    //   ql                                    @ 37748736  ( 8,388,608)
    //   kh                                    @ 46137344  ( 8,388,608)
    //   kl                                    @ 54525952  ( 8,388,608)
    //   vb  bf16 [32][2048][64]               @ 62914560  ( 8,388,608)
    //   vt  bf16 [32][64][2048]               @ 71303168  ( 8,388,608)
    char* ws = (char*)d_ws;
    ushort_t* wh  = (ushort_t*)(ws);
    ushort_t* wl  = (ushort_t*)(ws + 6291456);
    ushort_t* xh  = (ushort_t*)(ws + 12582912);
    ushort_t* xl  = (ushort_t*)(ws + 20971520);
    ushort_t* qh  = (ushort_t*)(ws + 29360128);
    ushort_t* ql  = (ushort_t*)(ws + 37748736);
    ushort_t* kh  = (ushort_t*)(ws + 46137344);
    ushort_t* kl  = (ushort_t*)(ws + 54525952);
    ushort_t* vb  = (ushort_t*)(ws + 62914560);
    ushort_t* vt  = (ushort_t*)(ws + 71303168);
    ushort_t* yb  = xh;
    ushort_t* wph = xl;

    const dim3 blk(256);

    split_hilo_f32<<<dim3(2048), blk, 0, stream>>>(x, xh, xl, M_TOTAL * DMODEL / 4);
    split_hilo_f32<<<dim3(2048), blk, 0, stream>>>(w_qkv, wh, wl, 3 * DMODEL * DMODEL / 4);

    // qkv GEMM: writes qh/ql/kh/kl/vb directly (no fp32 qkv)
    gemm_bf16_nt<1><<<dim3(3 * DMODEL / 128, M_TOTAL / 128), blk, 0, stream>>>(
        xh, xl, wh, wl, nullptr, nullptr, qh, ql, kh, kl, vb,
        M_TOTAL, 3 * DMODEL, DMODEL);

    conv_f32_bf16<<<dim3(1024), blk, 0, stream>>>(w_proj, wph, DMODEL * DMODEL / 4);

    transpose_v<<<dim3(CTXLEN / 64, BATCH * NHEAD), blk, 0, stream>>>(vb, vt);

    attn_fwd2<<<dim3(1024), blk, 0, stream>>>(qh, ql, kh, kl, vt, yb);

    gemm_bf16_nt<0><<<dim3(DMODEL / 128, M_TOTAL / 128), blk, 0, stream>>>(
        yb, nullptr, wph, nullptr, b_proj, out, nullptr, nullptr, nullptr, nullptr, nullptr,
        M_TOTAL, DMODEL, DMODEL);
}